// Round 1
// baseline (306.721 us; speedup 1.0000x reference)
//
#include <hip/hip_runtime.h>
#include <math.h>

// ---- fixed CT geometry (matches reference) ----
#define IMG    512
#define NDET   768
#define NVIEWS 360
#define BATCH  2
#define PIX    0.7433f
#define DSO_F  595.0f
#define DSO_D  595.0
#define DSD_D  (595.0 + 490.6)
#define DGAMMA_D (1.2858 / DSD_D)
#define DGAMMA_F ((float)DGAMMA_D)
#define GLEN   (2 * NDET - 1)   // 1535 ramp taps

// ---------------------------------------------------------------------------
// Kernel 0: build the Kak-Slaney equiangular ramp kernel g(n*dgamma), f64->f32
// ---------------------------------------------------------------------------
__global__ void ramp_init_kernel(float* __restrict__ g) {
    int idx = blockIdx.x * blockDim.x + threadIdx.x;
    if (idx >= GLEN) return;
    int n = idx - (NDET - 1);
    double val;
    if (n == 0) {
        val = 1.0 / (8.0 * DGAMMA_D * DGAMMA_D);
    } else if (n & 1) {
        double s = M_PI * sin((double)n * DGAMMA_D);
        val = -0.5 / (s * s);
    } else {
        val = 0.0;
    }
    g[idx] = (float)val;
}

// ---------------------------------------------------------------------------
// Kernel 1: cosine weighting + direct ramp convolution (replaces rfft/irfft).
// One block per (batch,view) row. The FFT slice [NDET-1 : 2*NDET-1] is
// alias-free (wrap lands in 0..253), so linear convolution is exact.
// f64 accumulation: direct sum has heavy cancellation vs the 8.9e4 center tap.
// ---------------------------------------------------------------------------
__global__ __launch_bounds__(256) void filter_kernel(
        const float* __restrict__ proj,   // [BATCH*NVIEWS, NDET]
        const float* __restrict__ g,      // [GLEN]
        float* __restrict__ q) {          // [BATCH*NVIEWS, NDET]
    __shared__ float g_s[GLEN];
    __shared__ float p1_s[NDET];

    const int row = blockIdx.x;           // b*NVIEWS + v
    const int tid = threadIdx.x;

    for (int i = tid; i < GLEN; i += 256) g_s[i] = g[i];

    const float* prow = proj + (size_t)row * NDET;
    for (int j = tid; j < NDET; j += 256) {
        float gam = ((float)j - (NDET - 1) * 0.5f) * DGAMMA_F;
        p1_s[j] = prow[j] * (DSO_F * cosf(gam));
    }
    __syncthreads();

    for (int i = tid; i < NDET; i += 256) {
        const float* gi = g_s + i + (NDET - 1);   // g index = i - j + (NDET-1)
        double acc = 0.0;
        #pragma unroll 4
        for (int j = 0; j < NDET; ++j) {
            acc += (double)(p1_s[j] * gi[-j]);
        }
        q[(size_t)row * NDET + i] = (float)(acc * DGAMMA_D);
    }
}

// ---------------------------------------------------------------------------
// Kernel 2: pixel-driven equiangular fan-beam backprojection.
// One thread per pixel, both batches. gidx is batch-independent.
// In-bounds requires |gamma| <= 383.5*DGAMMA = 0.454 rad < pi/2, so
// atan2(cross,dot) == atanf(cross/dot) whenever dot > 0; dot <= 0 is
// always out of bounds.
// ---------------------------------------------------------------------------
__global__ __launch_bounds__(256) void backproject_kernel(
        const float* __restrict__ q,      // [BATCH, NVIEWS, NDET]
        float* __restrict__ out) {        // [BATCH, IMG, IMG]
    __shared__ float cb_s[NVIEWS];
    __shared__ float sb_s[NVIEWS];

    const int tid = threadIdx.x;
    for (int v = tid; v < NVIEWS; v += 256) {
        float beta = (float)((double)v * (2.0 * M_PI / (double)NVIEWS));
        float s, c;
        sincosf(beta, &s, &c);
        cb_s[v] = c;
        sb_s[v] = s;
    }
    __syncthreads();

    const int idx = blockIdx.x * 256 + tid;
    const int r  = idx >> 9;          // row    -> y
    const int cc = idx & 511;         // column -> x
    const float x = ((float)cc - (IMG - 1) * 0.5f) * PIX;
    const float y = ((float)r  - (IMG - 1) * 0.5f) * PIX;

    const float inv_dg = 1.0f / DGAMMA_F;
    float acc0 = 0.0f, acc1 = 0.0f;

    for (int v = 0; v < NVIEWS; ++v) {
        const float cb = cb_s[v];
        const float sb = sb_s[v];
        const float vx = x - DSO_F * cb;
        const float vy = y - DSO_F * sb;
        const float dot   = -(cb * vx + sb * vy);
        const float cross = -(cb * vy - sb * vx);

        if (dot > 0.0f) {
            const float gidx = atanf(cross / dot) * inv_dg + (NDET - 1) * 0.5f;
            if (gidx >= 0.0f && gidx <= (float)(NDET - 1)) {
                int i0 = (int)floorf(gidx);
                i0 = min(max(i0, 0), NDET - 2);
                float w = gidx - (float)i0;
                w = fminf(fmaxf(w, 0.0f), 1.0f);
                const float L2 = vx * vx + vy * vy;
                const float rl2 = 1.0f / L2;

                const float* q0 = q + (size_t)v * NDET + i0;
                const float* q1 = q0 + (size_t)NVIEWS * NDET;
                const float v00 = q0[0], v01 = q0[1];
                const float v10 = q1[0], v11 = q1[1];

                acc0 += (v00 * (1.0f - w) + v01 * w) * rl2;
                acc1 += (v10 * (1.0f - w) + v11 * w) * rl2;
            }
        }
    }

    const float SCALE = (float)(2.0 * M_PI / (double)NVIEWS);
    out[idx]             = acc0 * SCALE;
    out[idx + IMG * IMG] = acc1 * SCALE;
}

// ---------------------------------------------------------------------------
extern "C" void kernel_launch(void* const* d_in, const int* in_sizes, int n_in,
                              void* d_out, int out_size, void* d_ws, size_t ws_size,
                              hipStream_t stream) {
    const float* proj = (const float*)d_in[0];   // [2, 360, 768] f32
    float* out = (float*)d_out;                  // [2, 512, 512] f32

    // workspace layout: g table (2048 floats, 1535 used) then q sinogram
    float* g_ws = (float*)d_ws;
    float* q_ws = g_ws + 2048;                   // [2*360, 768] f32 = 2.1 MB

    ramp_init_kernel<<<(GLEN + 255) / 256, 256, 0, stream>>>(g_ws);
    filter_kernel<<<BATCH * NVIEWS, 256, 0, stream>>>(proj, g_ws, q_ws);
    backproject_kernel<<<(IMG * IMG) / 256, 256, 0, stream>>>(q_ws, out);
}

// Round 8
// 221.549 us; speedup vs baseline: 1.3844x; 1.3844x over previous
//
#include <hip/hip_runtime.h>
#include <math.h>

// ---- fixed CT geometry (matches reference) ----
#define IMG    512
#define NPIX   (IMG * IMG)
#define NDET   768
#define NVIEWS 360
#define VHALF  180
#define BATCH  2
#define PIX    0.7433f
#define DSO_F  595.0f
#define DSD_D  (595.0 + 490.6)
#define DGAMMA_D (1.2858 / DSD_D)
#define DGAMMA_F ((float)DGAMMA_D)
#define GPAD   1536              // 1535 ramp taps + 1 pad (tap 1535 = n=+768 even = 0)

// ---------------------------------------------------------------------------
// Kernel 0: Kak-Slaney equiangular ramp kernel g(n*dgamma), f64 -> f32.
// ---------------------------------------------------------------------------
__global__ void ramp_init_kernel(float* __restrict__ g) {
    int idx = blockIdx.x * blockDim.x + threadIdx.x;
    if (idx >= GPAD) return;
    int n = idx - (NDET - 1);
    double val = 0.0;
    if (n == 0) {
        val = 1.0 / (8.0 * DGAMMA_D * DGAMMA_D);
    } else if (n & 1) {
        double s = M_PI * sin((double)n * DGAMMA_D);
        val = -0.5 / (s * s);
    }
    g[idx] = (float)val;
}

// ---------------------------------------------------------------------------
// Kernel 1: cosine weighting + direct ramp convolution (alias-free linear
// conv == the reference's NFFT=2048 FFT slice: wrap lands in [0,253], slice
// is [767,1534]). Register-blocked 4 outputs x 4 taps. f32 accumulation:
// q error ~0.07 rms -> <1e-7 of output scale after 1/L^2 backprojection.
// ---------------------------------------------------------------------------
__global__ __launch_bounds__(192) void filter_kernel(
        const float* __restrict__ proj,   // [BATCH*NVIEWS, NDET]
        const float* __restrict__ g,      // [GPAD]
        float* __restrict__ q) {          // [BATCH*NVIEWS, NDET]
    __shared__ __align__(16) float g_s[GPAD];
    __shared__ __align__(16) float p1_s[NDET];

    const int row = blockIdx.x;
    const int tid = threadIdx.x;

    for (int i = tid; i < GPAD; i += 192) g_s[i] = g[i];

    const float* prow = proj + (size_t)row * NDET;
    for (int j = tid; j < NDET; j += 192) {
        float gam = ((float)j - (NDET - 1) * 0.5f) * DGAMMA_F;
        p1_s[j] = prow[j] * (DSO_F * cosf(gam));
    }
    __syncthreads();

    const int i0 = 4 * tid;
    float a0 = 0.f, a1 = 0.f, a2 = 0.f, a3 = 0.f;

    #pragma unroll 4
    for (int jb = 0; jb < NDET / 4; ++jb) {
        const float4 p  = *(const float4*)&p1_s[4 * jb];
        const int base  = i0 - 4 * jb + 764;          // in [0, 1528], 16B aligned
        const float4 ga = *(const float4*)&g_s[base];
        const float4 gb = *(const float4*)&g_s[base + 4];
        // q[i0+k] += sum_m p[m] * g_s[base + (k+3-m)]
        a0 = fmaf(p.x, ga.w, a0); a0 = fmaf(p.y, ga.z, a0);
        a0 = fmaf(p.z, ga.y, a0); a0 = fmaf(p.w, ga.x, a0);
        a1 = fmaf(p.x, gb.x, a1); a1 = fmaf(p.y, ga.w, a1);
        a1 = fmaf(p.z, ga.z, a1); a1 = fmaf(p.w, ga.y, a1);
        a2 = fmaf(p.x, gb.y, a2); a2 = fmaf(p.y, gb.x, a2);
        a2 = fmaf(p.z, ga.w, a2); a2 = fmaf(p.w, ga.z, a2);
        a3 = fmaf(p.x, gb.z, a3); a3 = fmaf(p.y, gb.y, a3);
        a3 = fmaf(p.z, gb.x, a3); a3 = fmaf(p.w, ga.w, a3);
    }

    const float s = DGAMMA_F;
    *(float4*)&q[(size_t)row * NDET + i0] =
        make_float4(a0 * s, a1 * s, a2 * s, a3 * s);
}

// ---------------------------------------------------------------------------
// Kernel 2: pixel-driven fan-beam backprojection, view-split x2 for occupancy.
//   dot   = DSO - cb*x - sb*y  (always in [214, 976] -> no sign/0 hazard)
//   cross = sb*x - cb*y,  L2 = dot^2 + cross^2 (exact: rotation-invariant)
// gidx accuracy is CRITICAL: the reference's hard in-bounds cutoff at
// gidx in [0,767] means a gidx error of eps bins flips inclusion for
// ~94M*2*eps/768 pixel-view pairs, each flip injecting up to ~1e-2 into one
// output pixel (the round-4 failure: deg-15 poly, 2.6e-4 bins -> 1.2e-2).
// Now: deg-21 odd Taylor (trunc 3e-9 rad = 1.2e-5 bins at |t|<=0.489) +
// one Newton step on rcp(dot) (t division-accurate) -> ~3e-5 bins total,
// at or below the f32-atanf floor that passed at 9.77e-4.
// ---------------------------------------------------------------------------
__global__ __launch_bounds__(256) void backproject_kernel(
        const float* __restrict__ q,      // [BATCH, NVIEWS, NDET]
        float* __restrict__ out) {        // [BATCH, IMG, IMG] (pre-zeroed)
    __shared__ float2 trig[VHALF];

    const int bid = blockIdx.x;
    const int h   = bid & 1;              // view half
    const int pb  = bid >> 1;             // pixel block
    const int tid = threadIdx.x;

    if (tid < VHALF) {
        int v = h * VHALF + tid;
        double beta = (double)v * (2.0 * M_PI / (double)NVIEWS);
        trig[tid] = make_float2((float)cos(beta), (float)sin(beta));
    }
    __syncthreads();

    const int idx = pb * 256 + tid;
    const int r  = idx >> 9;
    const int cc = idx & 511;
    const float x = ((float)cc - 255.5f) * PIX;
    const float y = ((float)r  - 255.5f) * PIX;
    const float inv_dg = (float)(1.0 / DGAMMA_D);

    float acc0 = 0.0f, acc1 = 0.0f;
    int qoff = h * VHALF * NDET;

    for (int v = 0; v < VHALF; ++v, qoff += NDET) {
        const float2 cs = trig[v];
        const float cb = cs.x, sb = cs.y;
        const float dot   = fmaf(-sb, y, fmaf(-cb, x, DSO_F));
        const float cross = fmaf(-cb, y, sb * x);
        // Newton-refined reciprocal: rel err ~ulp (plain v_rcp's 1.2e-7
        // would cost 1e-4 gidx bins -> boundary-flip risk)
        float rd = __builtin_amdgcn_rcpf(dot);
        rd = fmaf(rd, fmaf(-dot, rd, 1.0f), rd);
        const float t = cross * rd;
        const float u = t * t;

        if (u <= 0.2704f) {               // |t|<=0.52; in-bounds needs <=0.4887
            // atan(t) = t + t*u*S, deg-21 odd Taylor
            float s = fmaf(u, 0.04761905f, -0.05263158f);   //  1/21, -1/19
            s = fmaf(u, s,  0.05882353f);                   //  1/17
            s = fmaf(u, s, -0.06666667f);                   // -1/15
            s = fmaf(u, s,  0.07692308f);                   //  1/13
            s = fmaf(u, s, -0.09090909f);                   // -1/11
            s = fmaf(u, s,  0.11111111f);                   //  1/9
            s = fmaf(u, s, -0.14285715f);                   // -1/7
            s = fmaf(u, s,  0.20000000f);                   //  1/5
            s = fmaf(u, s, -0.33333334f);                   // -1/3
            const float at   = fmaf(t * u, s, t);
            const float gidx = fmaf(at, inv_dg, 383.5f);

            if (gidx >= 0.0f && gidx <= 767.0f) {
                const int   i0 = min((int)gidx, 766);
                const float w  = gidx - (float)i0;
                const float rl2 =
                    __builtin_amdgcn_rcpf(fmaf(dot, dot, cross * cross));
                const int o = qoff + i0;
                const float v00 = q[o],                  v01 = q[o + 1];
                const float v10 = q[o + NVIEWS * NDET],  v11 = q[o + NVIEWS * NDET + 1];
                acc0 = fmaf(fmaf(w, v01 - v00, v00), rl2, acc0);
                acc1 = fmaf(fmaf(w, v11 - v10, v10), rl2, acc1);
            }
        }
    }

    const float SCALE = (float)(2.0 * M_PI / (double)NVIEWS);
    atomicAdd(&out[idx],        acc0 * SCALE);
    atomicAdd(&out[idx + NPIX], acc1 * SCALE);
}

// ---------------------------------------------------------------------------
extern "C" void kernel_launch(void* const* d_in, const int* in_sizes, int n_in,
                              void* d_out, int out_size, void* d_ws, size_t ws_size,
                              hipStream_t stream) {
    const float* proj = (const float*)d_in[0];   // [2, 360, 768] f32
    float* out = (float*)d_out;                  // [2, 512, 512] f32

    float* g_ws = (float*)d_ws;                  // 1536 floats
    float* q_ws = g_ws + GPAD;                   // [2*360, 768] f32

    hipMemsetAsync(out, 0, (size_t)BATCH * NPIX * sizeof(float), stream);
    ramp_init_kernel<<<(GPAD + 255) / 256, 256, 0, stream>>>(g_ws);
    filter_kernel<<<BATCH * NVIEWS, 192, 0, stream>>>(proj, g_ws, q_ws);
    backproject_kernel<<<(NPIX / 256) * 2, 256, 0, stream>>>(q_ws, out);
}

// Round 10
// 171.304 us; speedup vs baseline: 1.7905x; 1.2933x over previous
//
#include <hip/hip_runtime.h>
#include <math.h>

// ---- fixed CT geometry (matches reference) ----
#define IMG    512
#define NPIX   (IMG * IMG)
#define NDET   768
#define NVIEWS 360
#define BATCH  2
#define PIX    0.7433f
#define DSO_F  595.0f
#define DSD_D  (595.0 + 490.6)
#define DGAMMA_D (1.2858 / DSD_D)
#define DGAMMA_F ((float)DGAMMA_D)

// workspace float-index layout
#define WS_G2    0        // [0,1536): gE[768] then gEs[768]
#define WS_G0    1536     // scalar center tap
#define WS_TRIG  1538     // float2[360] at 8B-aligned float offset
#define WS_Q     2304     // [2*360*768] sinogram
#define QROWB    (NDET * 4)            // 3072 bytes per q row
#define QTOTB    (NVIEWS * QROWB)      // 1105920 bytes per batch
#define CHUNKS   8
#define VPC      (NVIEWS / CHUNKS)     // 45 views per chunk

// ---------------------------------------------------------------------------
// Kernel 0: compacted ramp tables + trig table (f64 -> f32).
// Ramp g(n) is zero for even n != 0, so store only odd taps:
//   gE[m]  = g_full[2m]   (tap n = 2m-767, odd)   m in [0,768)
//   gEs[k] = gE[k+1]                               (aligned copy for odd outputs)
//   g0     = 1/(8*dgamma^2)                        (center tap)
// Trig: (cos,sin)(v*2pi/360) as float2[360].
// ---------------------------------------------------------------------------
__global__ void ramp_init_kernel(float* __restrict__ ws) {
    int idx = blockIdx.x * blockDim.x + threadIdx.x;
    if (idx < 768) {
        int n = 2 * idx - 767;                      // odd
        double s = M_PI * sin((double)n * DGAMMA_D);
        ws[WS_G2 + idx] = (float)(-0.5 / (s * s));
    } else if (idx < 1536) {
        int k = idx - 768;
        if (k == 767) { ws[WS_G2 + idx] = 0.0f; }
        else {
            int n = 2 * k - 765;                    // = 2(k+1)-767, odd
            double s = M_PI * sin((double)n * DGAMMA_D);
            ws[WS_G2 + idx] = (float)(-0.5 / (s * s));
        }
    } else if (idx == 1536) {
        ws[WS_G0] = (float)(1.0 / (8.0 * DGAMMA_D * DGAMMA_D));
    } else if (idx >= 1600 && idx < 1600 + NVIEWS) {
        int v = idx - 1600;
        double b = (double)v * (2.0 * M_PI / (double)NVIEWS);
        ((float2*)(ws + WS_TRIG))[v] = make_float2((float)cos(b), (float)sin(b));
    }
}

// ---------------------------------------------------------------------------
// Kernel 1: cosine weighting + compacted ramp convolution.
// Half the full ramp's taps are zero (even n) -> 385 real MACs/output, not 768.
// q[2a]   = g0*pE[a] + sum_b gE [a+383-b]*pO[b]
// q[2a+1] = g0*pO[a] + sum_b gEs[a+383-b]*pE[b]     (gEs = gE shifted by 1,
//   stored separately so float4 windows stay 16B-aligned for both parities)
// Threads 0..95: 4 even outputs each; 96..191: 4 odd outputs. Register tile
// 4 outputs x 4 taps: 2 per-lane float4 g reads + 1 uniform float4 p read
// per 16 FMA. f32 accumulation (error attenuated ~3e-6 into the output).
// ---------------------------------------------------------------------------
__global__ __launch_bounds__(192) void filter_kernel(
        const float* __restrict__ proj,   // [BATCH*NVIEWS, NDET]
        const float* __restrict__ ws,     // tables
        float* __restrict__ q) {          // [BATCH*NVIEWS, NDET]
    __shared__ __align__(16) float g2_s[1536];     // gE | gEs
    __shared__ __align__(16) float pE_s[384];
    __shared__ __align__(16) float pO_s[384];

    const int row = blockIdx.x;
    const int tid = threadIdx.x;

    // stage tables (float4: 384 vecs / 192 threads = 2 each)
    ((float4*)g2_s)[tid]       = ((const float4*)(ws + WS_G2))[tid];
    ((float4*)g2_s)[tid + 192] = ((const float4*)(ws + WS_G2))[tid + 192];
    const float g0 = ws[WS_G0];

    // stage cosine-weighted projection row, split by parity
    const float* prow = proj + (size_t)row * NDET;
    for (int j = tid; j < NDET; j += 192) {
        float gam = ((float)j - (NDET - 1) * 0.5f) * DGAMMA_F;
        float val = prow[j] * (DSO_F * cosf(gam));
        if (j & 1) pO_s[j >> 1] = val; else pE_s[j >> 1] = val;
    }
    __syncthreads();

    const int  odd = (tid >= 96) ? 1 : 0;
    const int  s   = odd ? tid - 96 : tid;           // output group a = 4s+delta
    const float* gbase = g2_s + (odd ? 768 : 0);
    const float* pbase = odd ? pE_s : pO_s;          // conv source (opposite parity)
    const float* cbase = odd ? pO_s : pE_s;          // center term (own parity)

    float a0 = 0.f, a1 = 0.f, a2 = 0.f, a3 = 0.f;

    #pragma unroll 4
    for (int beta = 0; beta < 96; ++beta) {
        const float4 p4 = *(const float4*)&pbase[4 * beta];
        const int W = 4 * s + 380 - 4 * beta;        // in [0,760], mult of 4
        const float4 ga = *(const float4*)&gbase[W];
        const float4 gb = *(const float4*)&gbase[W + 4];
        // acc_d uses g[W+3+d-e]
        a0 = fmaf(p4.x, ga.w, a0); a0 = fmaf(p4.y, ga.z, a0);
        a0 = fmaf(p4.z, ga.y, a0); a0 = fmaf(p4.w, ga.x, a0);
        a1 = fmaf(p4.x, gb.x, a1); a1 = fmaf(p4.y, ga.w, a1);
        a1 = fmaf(p4.z, ga.z, a1); a1 = fmaf(p4.w, ga.y, a1);
        a2 = fmaf(p4.x, gb.y, a2); a2 = fmaf(p4.y, gb.x, a2);
        a2 = fmaf(p4.z, ga.w, a2); a2 = fmaf(p4.w, ga.z, a2);
        a3 = fmaf(p4.x, gb.z, a3); a3 = fmaf(p4.y, gb.y, a3);
        a3 = fmaf(p4.z, gb.x, a3); a3 = fmaf(p4.w, ga.w, a3);
    }

    // center tap + scale, store (outputs i = 8s + 2*delta + odd)
    float* qrow = q + (size_t)row * NDET + 8 * s + odd;
    const float sc = DGAMMA_F;
    qrow[0] = (fmaf(g0, cbase[4 * s + 0], a0)) * sc;
    qrow[2] = (fmaf(g0, cbase[4 * s + 1], a1)) * sc;
    qrow[4] = (fmaf(g0, cbase[4 * s + 2], a2)) * sc;
    qrow[6] = (fmaf(g0, cbase[4 * s + 3], a3)) * sc;
}

// ---------------------------------------------------------------------------
// Kernel 2: quad-symmetric pixel-driven backprojection.
// With dot = DSO - cb*x - sb*y, cross = sb*x - cb*y, L2 = dot^2 + cross^2,
// the four pixel-view units
//   A=( x, y)@v,  B=( x,-y)@(360-v),  C=(-x, y)@(180-v),  D=(-x,-y)@(180+v)
// share dot, |cross|, L2: B,C see gidx_m = 383.5 - at/dg (exact mirror),
// D sees gidx_A. One geometry computation (rcp+Newton, deg-21 atan Taylor,
// rl2) serves 4 pixels x 2 batches = 8 interp units.
// Views split into 8 chunks of 45 -> 2048 blocks; each output address gets
// 8 atomicAdds into the memset-zeroed out.
// gidx accuracy (round-4 lesson): deg-21 Taylor (1.2e-5 bins) + Newton-refined
// rcp keeps boundary-flip error at the floor that passed at 9.77e-4.
// ---------------------------------------------------------------------------
__global__ __launch_bounds__(256) void backproject_kernel(
        const float* __restrict__ ws,     // trig table + q
        float* __restrict__ out) {        // [BATCH, IMG, IMG] (pre-zeroed)
    __shared__ float2 trig[VPC];

    const int chunk = blockIdx.x & (CHUNKS - 1);
    const int qb    = blockIdx.x >> 3;
    const int tid   = threadIdx.x;
    const int v0    = chunk * VPC;

    if (tid < VPC)
        trig[tid] = ((const float2*)(ws + WS_TRIG))[v0 + tid];
    __syncthreads();

    const int qidx = qb * 256 + tid;      // quad index in [0, 65536)
    const int r  = qidx >> 8;             // [0,256)
    const int cc = qidx & 255;            // [0,256)
    const float x = ((float)cc - 255.5f) * PIX;   // negative quadrant
    const float y = ((float)r  - 255.5f) * PIX;
    const float inv_dg = (float)(1.0 / DGAMMA_D);

    const char* q0 = (const char*)(ws + WS_Q);
    const char* q1 = q0 + QTOTB;

    // row byte-offsets for the four view streams
    int oA = v0 * QROWB;
    int oB = ((NVIEWS - v0) % NVIEWS) * QROWB;          // decrements, wraps at <0
    int oC = (((180 - v0) % NVIEWS + NVIEWS) % NVIEWS) * QROWB;  // decrements
    int oD = ((180 + v0) % NVIEWS) * QROWB;             // increments

    float aA0 = 0.f, aA1 = 0.f, aB0 = 0.f, aB1 = 0.f;
    float aC0 = 0.f, aC1 = 0.f, aD0 = 0.f, aD1 = 0.f;

    for (int i = 0; i < VPC; ++i) {
        const float2 cs = trig[i];
        const float cb = cs.x, sb = cs.y;
        const float dot   = fmaf(-sb, y, fmaf(-cb, x, DSO_F));  // >= 326 always
        const float cross = fmaf(-cb, y, sb * x);
        float rd = __builtin_amdgcn_rcpf(dot);
        rd = fmaf(rd, fmaf(-dot, rd, 1.0f), rd);                // Newton: ~ulp
        const float t = cross * rd;
        const float u = t * t;

        if (u <= 0.2704f) {               // |t|<=0.52; in-bounds needs <=0.4887
            float sp = fmaf(u, 0.04761905f, -0.05263158f);  //  1/21, -1/19
            sp = fmaf(u, sp,  0.05882353f);                 //  1/17
            sp = fmaf(u, sp, -0.06666667f);                 // -1/15
            sp = fmaf(u, sp,  0.07692308f);                 //  1/13
            sp = fmaf(u, sp, -0.09090909f);                 // -1/11
            sp = fmaf(u, sp,  0.11111111f);                 //  1/9
            sp = fmaf(u, sp, -0.14285715f);                 // -1/7
            sp = fmaf(u, sp,  0.20000000f);                 //  1/5
            sp = fmaf(u, sp, -0.33333334f);                 // -1/3
            const float at   = fmaf(t * u, sp, t);
            const float gidx = fmaf(at,  inv_dg, 383.5f);

            if (gidx >= 0.0f && gidx <= 767.0f) {
                const float gm = fmaf(at, -inv_dg, 383.5f); // exact mirror form
                const int i0  = min((int)gidx, 766);
                const int i0m = min((int)gm,   766);
                const float w  = gidx - (float)i0;
                const float wm = gm   - (float)i0m;
                const float rl2 =
                    __builtin_amdgcn_rcpf(fmaf(dot, dot, cross * cross));

                const int bA = oA + (i0  << 2);
                const int bB = oB + (i0m << 2);
                const int bC = oC + (i0m << 2);
                const int bD = oD + (i0  << 2);
                const float* pA0 = (const float*)(q0 + bA);
                const float* pB0 = (const float*)(q0 + bB);
                const float* pC0 = (const float*)(q0 + bC);
                const float* pD0 = (const float*)(q0 + bD);
                const float* pA1 = (const float*)(q1 + bA);
                const float* pB1 = (const float*)(q1 + bB);
                const float* pC1 = (const float*)(q1 + bC);
                const float* pD1 = (const float*)(q1 + bD);

                aA0 = fmaf(fmaf(w,  pA0[1] - pA0[0], pA0[0]), rl2, aA0);
                aB0 = fmaf(fmaf(wm, pB0[1] - pB0[0], pB0[0]), rl2, aB0);
                aC0 = fmaf(fmaf(wm, pC0[1] - pC0[0], pC0[0]), rl2, aC0);
                aD0 = fmaf(fmaf(w,  pD0[1] - pD0[0], pD0[0]), rl2, aD0);
                aA1 = fmaf(fmaf(w,  pA1[1] - pA1[0], pA1[0]), rl2, aA1);
                aB1 = fmaf(fmaf(wm, pB1[1] - pB1[0], pB1[0]), rl2, aB1);
                aC1 = fmaf(fmaf(wm, pC1[1] - pC1[0], pC1[0]), rl2, aC1);
                aD1 = fmaf(fmaf(w,  pD1[1] - pD1[0], pD1[0]), rl2, aD1);
            }
        }

        oA += QROWB;
        oB -= QROWB; if (oB < 0) oB += QTOTB;
        oC -= QROWB; if (oC < 0) oC += QTOTB;
        oD += QROWB; if (oD >= QTOTB) oD -= QTOTB;
    }

    const float SCALE = (float)(2.0 * M_PI / (double)NVIEWS);
    const int rM = 511 - r, cM = 511 - cc;
    atomicAdd(&out[(r  << 9) + cc],         aA0 * SCALE);
    atomicAdd(&out[(rM << 9) + cc],         aB0 * SCALE);
    atomicAdd(&out[(r  << 9) + cM],         aC0 * SCALE);
    atomicAdd(&out[(rM << 9) + cM],         aD0 * SCALE);
    atomicAdd(&out[(r  << 9) + cc  + NPIX], aA1 * SCALE);
    atomicAdd(&out[(rM << 9) + cc  + NPIX], aB1 * SCALE);
    atomicAdd(&out[(r  << 9) + cM  + NPIX], aC1 * SCALE);
    atomicAdd(&out[(rM << 9) + cM  + NPIX], aD1 * SCALE);
}

// ---------------------------------------------------------------------------
extern "C" void kernel_launch(void* const* d_in, const int* in_sizes, int n_in,
                              void* d_out, int out_size, void* d_ws, size_t ws_size,
                              hipStream_t stream) {
    const float* proj = (const float*)d_in[0];   // [2, 360, 768] f32
    float* out = (float*)d_out;                  // [2, 512, 512] f32
    float* ws  = (float*)d_ws;
    float* q   = ws + WS_Q;                      // [2*360, 768]

    hipMemsetAsync(out, 0, (size_t)BATCH * NPIX * sizeof(float), stream);
    ramp_init_kernel<<<8, 256, 0, stream>>>(ws);
    filter_kernel<<<BATCH * NVIEWS, 192, 0, stream>>>(proj, ws, q);
    backproject_kernel<<<(NPIX / 4 / 256) * CHUNKS, 256, 0, stream>>>(ws, out);
}